// Round 9
// baseline (73.852 us; speedup 1.0000x reference)
//
#include <hip/hip_runtime.h>
#include <hip/hip_cooperative_groups.h>

namespace cg = cooperative_groups;

#define KMAX 64
#define BB 4
#define LL 4096
#define DD 64
#define TOK (BB * LL)   // 16384 tokens per side
#define NBLK 512        // 512 x 256 = 2048 waves; needs only 2 blocks/CU -> safe coop
#define QPW 8           // queries per wave in fused phase B

typedef unsigned long long u64;

// ---------- Fused cooperative kernel ----------
// Phase A (gt < 2*TOK, i.e. blocks 0..127): token codes, math VERBATIM from
// the bitwise-verified codes_kernel (absmax 0.0 since R1) — strictly
// sequential d=0..63 accumulation; do NOT tree-reduce (floor() at bucket
// edges is order-sensitive).  grid.sync().  Phase B: 2048 waves x 8 queries;
// one int4 group load shared by 8 queries; ballot/popc ordered-write body
// verbatim from R6/R7.
__global__ __launch_bounds__(256) void fused_kernel(
        const float* __restrict__ q,
        const float* __restrict__ k,
        const float* __restrict__ W,
        int* __restrict__ codes /* ws: [0,TOK)=qcodes, [TOK,2*TOK)=kcodes */,
        int* __restrict__ out) {
    __shared__ float sW[DD * 4];
    int tid = threadIdx.x;
    sW[tid] = W[tid];                              // 256 threads = 256 floats
    __syncthreads();                               // uniform across all blocks

    int gt = blockIdx.x * 256 + tid;

    // ---------------- Phase A ----------------
    if (gt < 2 * TOK) {
        const float* src = (gt < TOK) ? q : k;
        int t = gt & (TOK - 1);
        const float4* xp = (const float4*)(src + (size_t)t * DD);
        float4 x[16];
        #pragma unroll
        for (int i = 0; i < 16; ++i) x[i] = xp[i];

        float p0 = 0.f, p1 = 0.f, p2 = 0.f, p3 = 0.f;
        const float4* wrow = (const float4*)sW;
        #pragma unroll
        for (int d = 0; d < DD; ++d) {
            float xv = ((const float*)x)[d];
            float b = (xv > 0.f) ? 1.0f : 0.0f;    // binary_quantize
            float4 w = wrow[d];
            p0 = fmaf(b, w.x, p0);
            p1 = fmaf(b, w.y, p1);
            p2 = fmaf(b, w.z, p2);
            p3 = fmaf(b, w.w, p3);
        }
        int h0 = ((int)floorf(p0 * 0.5f)) & 31;    // floor(p/2) mod 32
        int h1 = ((int)floorf(p1 * 0.5f)) & 31;
        int h2 = ((int)floorf(p2 * 0.5f)) & 31;
        int h3 = ((int)floorf(p3 * 0.5f)) & 31;
        codes[gt] = h0 | (h1 << 5) | (h2 << 10) | (h3 << 15);
    }

    cg::this_grid().sync();

    // ---------------- Phase B ----------------
    int lane = tid & 63;
    int wv = gt >> 6;                              // 0..2047
    int qbase = wv * QPW;                          // 8 queries, never crosses batch
    int b = qbase >> 12;
    const int4* kc4 = (const int4*)(codes + TOK + b * LL);
    const int* qp = codes + qbase;
    int* outb = out + (size_t)qbase * KMAX;
    u64 lowmask = (1ull << lane) - 1ull;

    int qc[QPW], cnt[QPW];
    #pragma unroll
    for (int i = 0; i < QPW; ++i) { qc[i] = qp[i]; cnt[i] = 0; }

    for (int g = 0; g < LL / 256; ++g) {           // 16 groups of 256 j
        int4 kv = kc4[g * 64 + lane];
        int j0 = g * 256 + lane * 4;
        #pragma unroll
        for (int i = 0; i < QPW; ++i) {            // full unroll: no runtime idx
            if (cnt[i] >= KMAX) continue;          // wave-uniform (ballot-derived)
            bool m0 = (kv.x == qc[i]), m1 = (kv.y == qc[i]);
            bool m2 = (kv.z == qc[i]), m3 = (kv.w == qc[i]);
            if (__ballot(m0 | m1 | m2 | m3) == 0) continue;
            u64 b0 = __ballot(m0), b1 = __ballot(m1);
            u64 b2 = __ballot(m2), b3 = __ballot(m3);
            int before = __popcll(b0 & lowmask) + __popcll(b1 & lowmask)
                       + __popcll(b2 & lowmask) + __popcll(b3 & lowmask);
            int pos = cnt[i] + before;
            int* op = outb + i * KMAX;
            if (m0) { if (pos < KMAX) op[pos] = j0;     ++pos; }
            if (m1) { if (pos < KMAX) op[pos] = j0 + 1; ++pos; }
            if (m2) { if (pos < KMAX) op[pos] = j0 + 2; ++pos; }
            if (m3) { if (pos < KMAX) op[pos] = j0 + 3; ++pos; }
            cnt[i] += __popcll(b0) + __popcll(b1) + __popcll(b2) + __popcll(b3);
        }
    }
    #pragma unroll
    for (int i = 0; i < QPW; ++i) {                // -1 tail fill
        int p = cnt[i] + lane;
        if (p < KMAX) outb[i * KMAX + p] = -1;
    }
}

// ---------- Fallback path: R7 kernels VERBATIM (proven, 23.7 us) ----------
__global__ __launch_bounds__(64) void codes_kernel(
        const float* __restrict__ q,
        const float* __restrict__ k,
        const float* __restrict__ W,
        int* __restrict__ codes) {
    __shared__ float sW[DD * 4];
    int lane = threadIdx.x;
    #pragma unroll
    for (int i = 0; i < 4; ++i) sW[i * 64 + lane] = W[i * 64 + lane];
    __syncthreads();
    int u = blockIdx.x * 64 + lane;
    const float* src = (u < TOK) ? q : k;
    int t = u & (TOK - 1);
    const float4* xp = (const float4*)(src + (size_t)t * DD);
    float4 x[16];
    #pragma unroll
    for (int i = 0; i < 16; ++i) x[i] = xp[i];
    float p0 = 0.f, p1 = 0.f, p2 = 0.f, p3 = 0.f;
    const float4* wrow = (const float4*)sW;
    #pragma unroll
    for (int d = 0; d < DD; ++d) {
        float xv = ((const float*)x)[d];
        float b = (xv > 0.f) ? 1.0f : 0.0f;
        float4 w = wrow[d];
        p0 = fmaf(b, w.x, p0);
        p1 = fmaf(b, w.y, p1);
        p2 = fmaf(b, w.z, p2);
        p3 = fmaf(b, w.w, p3);
    }
    int h0 = ((int)floorf(p0 * 0.5f)) & 31;
    int h1 = ((int)floorf(p1 * 0.5f)) & 31;
    int h2 = ((int)floorf(p2 * 0.5f)) & 31;
    int h3 = ((int)floorf(p3 * 0.5f)) & 31;
    codes[u] = h0 | (h1 << 5) | (h2 << 10) | (h3 << 15);
}

__global__ __launch_bounds__(256) void find_kernel(
        const int* __restrict__ qcodes,
        const int* __restrict__ kcodes,
        int* __restrict__ out) {
    int gtid = blockIdx.x * 256 + threadIdx.x;
    int wave = gtid >> 6;
    int lane = gtid & 63;
    int b = wave >> 12;
    int qc = qcodes[wave];
    const int4* kc4 = (const int4*)(kcodes + b * LL);
    int* op = out + (size_t)wave * KMAX;
    u64 lowmask = (1ull << lane) - 1ull;
    int count = 0;
    for (int g = 0; g < LL / 256 && count < KMAX; ++g) {
        int4 kv = kc4[g * 64 + lane];
        bool m0 = (kv.x == qc), m1 = (kv.y == qc);
        bool m2 = (kv.z == qc), m3 = (kv.w == qc);
        if (__ballot(m0 | m1 | m2 | m3) == 0) continue;
        u64 b0 = __ballot(m0), b1 = __ballot(m1);
        u64 b2 = __ballot(m2), b3 = __ballot(m3);
        int before = __popcll(b0 & lowmask) + __popcll(b1 & lowmask)
                   + __popcll(b2 & lowmask) + __popcll(b3 & lowmask);
        int pos = count + before;
        int j0 = g * 256 + lane * 4;
        if (m0) { if (pos < KMAX) op[pos] = j0;     ++pos; }
        if (m1) { if (pos < KMAX) op[pos] = j0 + 1; ++pos; }
        if (m2) { if (pos < KMAX) op[pos] = j0 + 2; ++pos; }
        if (m3) { if (pos < KMAX) op[pos] = j0 + 3; ++pos; }
        count += __popcll(b0) + __popcll(b1) + __popcll(b2) + __popcll(b3);
    }
    int p = count + lane;
    if (p < KMAX) op[p] = -1;
}

extern "C" void kernel_launch(void* const* d_in, const int* in_sizes, int n_in,
                              void* d_out, int out_size, void* d_ws, size_t ws_size,
                              hipStream_t stream) {
    const float* q = (const float*)d_in[0];
    const float* k = (const float*)d_in[1];
    const float* W = (const float*)d_in[2];
    int* out = (int*)d_out;
    int* codes = (int*)d_ws;                 // [2*TOK] ints (128 KB)

    void* args[] = {(void*)&q, (void*)&k, (void*)&W, (void*)&codes, (void*)&out};
    hipError_t e = hipLaunchCooperativeKernel((const void*)fused_kernel,
                                              dim3(NBLK), dim3(256), args, 0, stream);
    if (e != hipSuccess) {
        (void)hipGetLastError();             // clear sticky error, use proven path
        codes_kernel<<<(2 * TOK) / 64, 64, 0, stream>>>(q, k, W, codes);
        find_kernel<<<(TOK * 64) / 256, 256, 0, stream>>>(codes, codes + TOK, out);
    }
}

// Round 10
// 21.129 us; speedup vs baseline: 3.4952x; 3.4952x over previous
//
#include <hip/hip_runtime.h>

#define KMAX 64
#define BB 4
#define LL 4096
#define DD 64
#define TOK (BB * LL)   // 16384 tokens per side
#define QPW 4           // queries per wave (shares each int4 k-load 4 ways)

typedef unsigned long long u64;

// Phase 1 (verbatim, bitwise-verified absmax 0.0 since R1): one thread per
// token-side. Accumulation strictly sequential d=0..63 — DO NOT change to a
// tree reduction (floor() at bucket edges is order-sensitive).
__global__ __launch_bounds__(64) void codes_kernel(
        const float* __restrict__ q,
        const float* __restrict__ k,
        const float* __restrict__ W,
        int* __restrict__ codes /* [0,TOK)=qcodes, [TOK,2*TOK)=kcodes */) {
    __shared__ float sW[DD * 4];
    int lane = threadIdx.x;   // block = 64 = one wave
    #pragma unroll
    for (int i = 0; i < 4; ++i) sW[i * 64 + lane] = W[i * 64 + lane];
    __syncthreads();

    int u = blockIdx.x * 64 + lane;          // grid covers 2*TOK exactly
    const float* src = (u < TOK) ? q : k;
    int t = u & (TOK - 1);

    const float4* xp = (const float4*)(src + (size_t)t * DD);
    float4 x[16];
    #pragma unroll
    for (int i = 0; i < 16; ++i) x[i] = xp[i];

    float p0 = 0.f, p1 = 0.f, p2 = 0.f, p3 = 0.f;
    const float4* wrow = (const float4*)sW;
    #pragma unroll
    for (int d = 0; d < DD; ++d) {
        float xv = ((const float*)x)[d];
        float b = (xv > 0.f) ? 1.0f : 0.0f;      // binary_quantize
        float4 w = wrow[d];
        p0 = fmaf(b, w.x, p0);
        p1 = fmaf(b, w.y, p1);
        p2 = fmaf(b, w.z, p2);
        p3 = fmaf(b, w.w, p3);
    }
    int h0 = ((int)floorf(p0 * 0.5f)) & 31;      // floor(p/2) mod 32
    int h1 = ((int)floorf(p1 * 0.5f)) & 31;
    int h2 = ((int)floorf(p2 * 0.5f)) & 31;
    int h3 = ((int)floorf(p3 * 0.5f)) & 31;
    codes[u] = h0 | (h1 << 5) | (h2 << 10) | (h3 << 15);
}

// Phase 2: 4096 waves (4/SIMD), 4 queries per wave. Each int4 group load is
// shared by the 4 queries (L1 traffic /4 vs R7) and ONE combined ballot
// rejects all 4 queries for the usual no-match group. Per-query match body
// is verbatim from R6/R7/R9-phaseB (all absmax 0.0): lane-major
// j = g*256 + lane*4 + e; 'before' = sum of 4 ballots & lowmask; within-lane
// order via sequential pos++. cnt[] is ballot-derived -> wave-uniform skips.
__global__ __launch_bounds__(256) void find_kernel(
        const int* __restrict__ qcodes,
        const int* __restrict__ kcodes,
        int* __restrict__ out) {
    int gtid = blockIdx.x * 256 + threadIdx.x;
    int wave = gtid >> 6;                // 0..4095
    int lane = gtid & 63;
    int qbase = wave * QPW;              // 4 queries, never crosses a batch
    int b = qbase >> 12;
    const int4* kc4 = (const int4*)(kcodes + b * LL);
    const int* qp = qcodes + qbase;
    int* outb = out + (size_t)qbase * KMAX;
    u64 lowmask = (1ull << lane) - 1ull;

    int qc[QPW], cnt[QPW];
    #pragma unroll
    for (int i = 0; i < QPW; ++i) { qc[i] = qp[i]; cnt[i] = 0; }

    for (int g = 0; g < LL / 256; ++g) {           // 16 groups of 256 j
        int4 kv = kc4[g * 64 + lane];
        bool a0 = (kv.x == qc[0]) | (kv.y == qc[0]) | (kv.z == qc[0]) | (kv.w == qc[0]);
        bool a1 = (kv.x == qc[1]) | (kv.y == qc[1]) | (kv.z == qc[1]) | (kv.w == qc[1]);
        bool a2 = (kv.x == qc[2]) | (kv.y == qc[2]) | (kv.z == qc[2]) | (kv.w == qc[2]);
        bool a3 = (kv.x == qc[3]) | (kv.y == qc[3]) | (kv.z == qc[3]) | (kv.w == qc[3]);
        if (__ballot(a0 | a1 | a2 | a3) == 0) continue;    // usual case: 1 ballot/group
        int j0 = g * 256 + lane * 4;
        #pragma unroll
        for (int i = 0; i < QPW; ++i) {            // full unroll: no runtime idx
            if (cnt[i] >= KMAX) continue;          // wave-uniform
            bool m0 = (kv.x == qc[i]), m1 = (kv.y == qc[i]);
            bool m2 = (kv.z == qc[i]), m3 = (kv.w == qc[i]);
            if (__ballot(m0 | m1 | m2 | m3) == 0) continue;
            u64 b0 = __ballot(m0), b1 = __ballot(m1);
            u64 b2 = __ballot(m2), b3 = __ballot(m3);
            int before = __popcll(b0 & lowmask) + __popcll(b1 & lowmask)
                       + __popcll(b2 & lowmask) + __popcll(b3 & lowmask);
            int pos = cnt[i] + before;
            int* op = outb + i * KMAX;
            if (m0) { if (pos < KMAX) op[pos] = j0;     ++pos; }
            if (m1) { if (pos < KMAX) op[pos] = j0 + 1; ++pos; }
            if (m2) { if (pos < KMAX) op[pos] = j0 + 2; ++pos; }
            if (m3) { if (pos < KMAX) op[pos] = j0 + 3; ++pos; }
            cnt[i] += __popcll(b0) + __popcll(b1) + __popcll(b2) + __popcll(b3);
        }
    }
    #pragma unroll
    for (int i = 0; i < QPW; ++i) {                // -1 tail fill, coalesced
        int p = cnt[i] + lane;
        if (p < KMAX) outb[i * KMAX + p] = -1;
    }
}

extern "C" void kernel_launch(void* const* d_in, const int* in_sizes, int n_in,
                              void* d_out, int out_size, void* d_ws, size_t ws_size,
                              hipStream_t stream) {
    const float* q = (const float*)d_in[0];
    const float* k = (const float*)d_in[1];
    const float* W = (const float*)d_in[2];
    int* out = (int*)d_out;
    int* codes = (int*)d_ws;                 // [2*TOK] ints (128 KB)
    int* qcodes = codes;
    int* kcodes = codes + TOK;

    codes_kernel<<<(2 * TOK) / 64, 64, 0, stream>>>(q, k, W, codes);

    const int total_threads = (TOK / QPW) * 64;    // 4096 waves
    find_kernel<<<total_threads / 256, 256, 0, stream>>>(qcodes, kcodes, out);
}

// Round 11
// 20.902 us; speedup vs baseline: 3.5332x; 1.0109x over previous
//
#include <hip/hip_runtime.h>

#define KMAX 64
#define BB 4
#define LL 4096
#define DD 64
#define TOK (BB * LL)   // 16384 tokens per side
#define QPW 4           // queries per wave

typedef unsigned long long u64;

// Phase 1: math VERBATIM (bitwise-verified absmax 0.0 since R1): strictly
// sequential d=0..63 accumulation — DO NOT tree-reduce (floor() at bucket
// edges is order-sensitive). Regrouped to 256-thread blocks (same per-thread
// work, 4x fewer blocks).
__global__ __launch_bounds__(256) void codes_kernel(
        const float* __restrict__ q,
        const float* __restrict__ k,
        const float* __restrict__ W,
        int* __restrict__ codes /* [0,TOK)=qcodes, [TOK,2*TOK)=kcodes */) {
    __shared__ float sW[DD * 4];
    int tid = threadIdx.x;
    sW[tid] = W[tid];                        // 256 threads = 256 floats
    __syncthreads();

    int u = blockIdx.x * 256 + tid;          // grid covers 2*TOK exactly
    const float* src = (u < TOK) ? q : k;
    int t = u & (TOK - 1);

    const float4* xp = (const float4*)(src + (size_t)t * DD);
    float4 x[16];
    #pragma unroll
    for (int i = 0; i < 16; ++i) x[i] = xp[i];

    float p0 = 0.f, p1 = 0.f, p2 = 0.f, p3 = 0.f;
    const float4* wrow = (const float4*)sW;
    #pragma unroll
    for (int d = 0; d < DD; ++d) {
        float xv = ((const float*)x)[d];
        float b = (xv > 0.f) ? 1.0f : 0.0f;      // binary_quantize
        float4 w = wrow[d];
        p0 = fmaf(b, w.x, p0);
        p1 = fmaf(b, w.y, p1);
        p2 = fmaf(b, w.z, p2);
        p3 = fmaf(b, w.w, p3);
    }
    int h0 = ((int)floorf(p0 * 0.5f)) & 31;      // floor(p/2) mod 32
    int h1 = ((int)floorf(p1 * 0.5f)) & 31;
    int h2 = ((int)floorf(p2 * 0.5f)) & 31;
    int h3 = ((int)floorf(p3 * 0.5f)) & 31;
    codes[u] = h0 | (h1 << 5) | (h2 << 10) | (h3 << 15);
}

// Phase 2: 4096 waves, 4 queries per wave. ALL 16 group loads issued
// up-front (the wave's 64 lanes x 16 int4 = the entire 4096-code batch in
// registers) -> memory latency paid once, not 16x (the R10 latency-chain
// diagnosis). Processing per group is VERBATIM from R10 (absmax 0.0):
// combined 1-ballot reject, then per-query lane-major ordered write
// (j = g*256 + lane*4 + e; before = sum of 4 ballots & lowmask; within-lane
// order via sequential pos++). cnt[] ballot-derived -> wave-uniform skips.
__global__ __launch_bounds__(256) void find_kernel(
        const int* __restrict__ qcodes,
        const int* __restrict__ kcodes,
        int* __restrict__ out) {
    int gtid = blockIdx.x * 256 + threadIdx.x;
    int wave = gtid >> 6;                // 0..4095
    int lane = gtid & 63;
    int qbase = wave * QPW;              // 4 queries, never crosses a batch
    int b = qbase >> 12;
    const int4* kc4 = (const int4*)(kcodes + b * LL);
    const int* qp = qcodes + qbase;
    int* outb = out + (size_t)qbase * KMAX;
    u64 lowmask = (1ull << lane) - 1ull;

    // ---- prefetch the whole batch into registers (16 independent loads) ----
    int4 kv[16];
    #pragma unroll
    for (int g = 0; g < 16; ++g) kv[g] = kc4[g * 64 + lane];

    int qc[QPW], cnt[QPW];
    #pragma unroll
    for (int i = 0; i < QPW; ++i) { qc[i] = qp[i]; cnt[i] = 0; }

    #pragma unroll
    for (int g = 0; g < 16; ++g) {                 // 16 groups of 256 j
        bool a0 = (kv[g].x == qc[0]) | (kv[g].y == qc[0]) | (kv[g].z == qc[0]) | (kv[g].w == qc[0]);
        bool a1 = (kv[g].x == qc[1]) | (kv[g].y == qc[1]) | (kv[g].z == qc[1]) | (kv[g].w == qc[1]);
        bool a2 = (kv[g].x == qc[2]) | (kv[g].y == qc[2]) | (kv[g].z == qc[2]) | (kv[g].w == qc[2]);
        bool a3 = (kv[g].x == qc[3]) | (kv[g].y == qc[3]) | (kv[g].z == qc[3]) | (kv[g].w == qc[3]);
        if (__ballot(a0 | a1 | a2 | a3) == 0) continue;    // usual case
        int j0 = g * 256 + lane * 4;
        #pragma unroll
        for (int i = 0; i < QPW; ++i) {            // full unroll: no runtime idx
            if (cnt[i] >= KMAX) continue;          // wave-uniform
            bool m0 = (kv[g].x == qc[i]), m1 = (kv[g].y == qc[i]);
            bool m2 = (kv[g].z == qc[i]), m3 = (kv[g].w == qc[i]);
            if (__ballot(m0 | m1 | m2 | m3) == 0) continue;
            u64 b0 = __ballot(m0), b1 = __ballot(m1);
            u64 b2 = __ballot(m2), b3 = __ballot(m3);
            int before = __popcll(b0 & lowmask) + __popcll(b1 & lowmask)
                       + __popcll(b2 & lowmask) + __popcll(b3 & lowmask);
            int pos = cnt[i] + before;
            int* op = outb + i * KMAX;
            if (m0) { if (pos < KMAX) op[pos] = j0;     ++pos; }
            if (m1) { if (pos < KMAX) op[pos] = j0 + 1; ++pos; }
            if (m2) { if (pos < KMAX) op[pos] = j0 + 2; ++pos; }
            if (m3) { if (pos < KMAX) op[pos] = j0 + 3; ++pos; }
            cnt[i] += __popcll(b0) + __popcll(b1) + __popcll(b2) + __popcll(b3);
        }
    }
    #pragma unroll
    for (int i = 0; i < QPW; ++i) {                // -1 tail fill, coalesced
        int p = cnt[i] + lane;
        if (p < KMAX) outb[i * KMAX + p] = -1;
    }
}

extern "C" void kernel_launch(void* const* d_in, const int* in_sizes, int n_in,
                              void* d_out, int out_size, void* d_ws, size_t ws_size,
                              hipStream_t stream) {
    const float* q = (const float*)d_in[0];
    const float* k = (const float*)d_in[1];
    const float* W = (const float*)d_in[2];
    int* out = (int*)d_out;
    int* codes = (int*)d_ws;                 // [2*TOK] ints (128 KB)
    int* qcodes = codes;
    int* kcodes = codes + TOK;

    codes_kernel<<<(2 * TOK) / 256, 256, 0, stream>>>(q, k, W, codes);

    const int total_threads = (TOK / QPW) * 64;    // 4096 waves
    find_kernel<<<total_threads / 256, 256, 0, stream>>>(qcodes, kcodes, out);
}